// Round 7
// baseline (131.372 us; speedup 1.0000x reference)
//
#include <hip/hip_runtime.h>
#include <hip/hip_bf16.h>
#include <math.h>

#define SEQ_LEN  8192
#define HIDDEN   1024
#define NUM_SPANS 4096
#define MAX_W    32

__device__ __forceinline__ float dot4(float4 a, float4 b) {
    return a.x * b.x + a.y * b.y + a.z * b.z + a.w * b.w;
}

// ---------------------------------------------------------------------------
// K1: s_all[r] = dot(emb[r], attn_w) + bias for all 8192 rows.
// Key insight: span scores depend only on the ABSOLUTE row index, so the
// 67K logical per-span row-dots collapse to 8192 row-dots computed once.
// Wave-per-row: 64 lanes x 4 float4 = 1024 floats, coalesced; butterfly
// reduce; lane 0 stores. 2048 blocks x 256 thr. Pure 32 MB stream.
// ---------------------------------------------------------------------------
__global__ __launch_bounds__(256, 4) void row_score_kernel(
    const float* __restrict__ emb,      // (SEQ_LEN, HIDDEN)
    const float* __restrict__ attn_w,   // (HIDDEN,)
    const float* __restrict__ attn_b,   // (1,)
    float* __restrict__ s_all)          // (SEQ_LEN,) workspace
{
    const int wv2 = threadIdx.x >> 6;   // wave 0..3
    const int c   = threadIdx.x & 63;   // lane
    const int row = blockIdx.x * 4 + wv2;

    const float4* __restrict__ r4 = (const float4*)emb + (size_t)row * 256;
    const float4* __restrict__ wv = (const float4*)attn_w;

    float4 a0 = r4[c];
    float4 a1 = r4[c + 64];
    float4 a2 = r4[c + 128];
    float4 a3 = r4[c + 192];
    float4 w0 = wv[c];
    float4 w1 = wv[c + 64];
    float4 w2 = wv[c + 128];
    float4 w3 = wv[c + 192];

    float p = dot4(a0, w0) + dot4(a1, w1) + dot4(a2, w2) + dot4(a3, w3);
    #pragma unroll
    for (int off = 32; off > 0; off >>= 1)
        p += __shfl_xor(p, off, 64);
    if (c == 0) s_all[row] = p + attn_b[0];
}

// ---------------------------------------------------------------------------
// K2: per span, out = [emb[start] | emb[end] | sum_w wt[w]*emb[start+w]].
// Wave-per-HALF-span (h in {0,1} covers 512 columns; lane c owns float4 cols
// h*128+c and h*128+64+c). ZERO barriers, ZERO LDS:
//   - weights known upfront (from s_all): 32-lane butterfly softmax, no
//     online rescaling, no cross-wave exchange.
//   - rows consumed in groups of 4: 8 independent float4 loads pinned above
//     the FMAs by sched_barrier(0) -> structural 8-deep MLP per wave, with
//     8192 waves of TLP on top. No barrier ever drains the pipeline.
// R6 post-mortem: the block-per-span chunk pipeline paid a vmcnt(0) drain at
// every __syncthreads (compiler-forced), ~10.5 us per block. This shape has
// no __syncthreads at all.
// ---------------------------------------------------------------------------
__global__ __launch_bounds__(256, 4) void span_out_kernel(
    const float* __restrict__ emb,      // (SEQ_LEN, HIDDEN)
    const int* __restrict__ starts,     // (NUM_SPANS,)
    const int* __restrict__ ends,       // (NUM_SPANS,)
    const float* __restrict__ s_all,    // (SEQ_LEN,) precomputed scores
    float* __restrict__ out)            // (NUM_SPANS, 3*HIDDEN)
{
    const int wv2 = threadIdx.x >> 6;       // wave 0..3
    const int c   = threadIdx.x & 63;       // lane
    const int s   = blockIdx.x * 2 + (wv2 >> 1);   // span
    const int h   = wv2 & 1;                       // half 0/1

    const int start = starts[s];
    const int end   = ends[s];
    const int wmax  = end - start;          // 0..31 inclusive width-1

    // ---- softmax weights from precomputed scores (both 32-halves dup) ----
    const int w = c & 31;
    float sc = (w <= wmax) ? s_all[start + w] : -INFINITY;
    float m = sc;
    #pragma unroll
    for (int off = 16; off > 0; off >>= 1)
        m = fmaxf(m, __shfl_xor(m, off, 32));
    float e = __expf(sc - m);               // invalid -> exp(-inf) = 0
    float l = e;
    #pragma unroll
    for (int off = 16; off > 0; off >>= 1)
        l += __shfl_xor(l, off, 32);
    const float wt = e / l;                 // lane w (and w+32) holds wt[w]

    const float4* __restrict__ embr = (const float4*)emb;
    const int basecol = h * 128 + c;                    // float4 column
    const size_t sb = (size_t)start * 256 + basecol;    // row 0 address

    float4 acc0 = make_float4(0.f, 0.f, 0.f, 0.f);
    float4 acc1 = make_float4(0.f, 0.f, 0.f, 0.f);
    float4 sv0, sv1;

    const int ng = (wmax >> 2) + 1;         // groups of 4 rows: 1..8

    // ---- group 0 peeled (captures start row from registers) --------------
    {
        const size_t q1 = (size_t)min(1, wmax) * 256;
        const size_t q2 = (size_t)min(2, wmax) * 256;
        const size_t q3 = (size_t)min(3, wmax) * 256;
        float4 a0 = embr[sb],      b0 = embr[sb + 64];
        float4 a1 = embr[sb + q1], b1 = embr[sb + q1 + 64];
        float4 a2 = embr[sb + q2], b2 = embr[sb + q2 + 64];
        float4 a3 = embr[sb + q3], b3 = embr[sb + q3 + 64];
        __builtin_amdgcn_sched_barrier(0);  // loads stay above the math

        sv0 = a0; sv1 = b0;
        const float t0 = __shfl(wt, 0, 64);
        const float t1 = __shfl(wt, 1, 64);   // wt==0 if 1..3 > wmax
        const float t2 = __shfl(wt, 2, 64);
        const float t3 = __shfl(wt, 3, 64);
        acc0.x += t0*a0.x + t1*a1.x + t2*a2.x + t3*a3.x;
        acc0.y += t0*a0.y + t1*a1.y + t2*a2.y + t3*a3.y;
        acc0.z += t0*a0.z + t1*a1.z + t2*a2.z + t3*a3.z;
        acc0.w += t0*a0.w + t1*a1.w + t2*a2.w + t3*a3.w;
        acc1.x += t0*b0.x + t1*b1.x + t2*b2.x + t3*b3.x;
        acc1.y += t0*b0.y + t1*b1.y + t2*b2.y + t3*b3.y;
        acc1.z += t0*b0.z + t1*b1.z + t2*b2.z + t3*b3.z;
        acc1.w += t0*b0.w + t1*b1.w + t2*b2.w + t3*b3.w;
    }

    // ---- groups 1..ng-1 --------------------------------------------------
    #pragma unroll 1
    for (int g = 1; g < ng; ++g) {
        const int r0 = 4 * g;               // r0 <= wmax guaranteed
        const size_t q0 = (size_t)r0 * 256;
        const size_t q1 = (size_t)min(r0 + 1, wmax) * 256;
        const size_t q2 = (size_t)min(r0 + 2, wmax) * 256;
        const size_t q3 = (size_t)min(r0 + 3, wmax) * 256;
        float4 a0 = embr[sb + q0], b0 = embr[sb + q0 + 64];
        float4 a1 = embr[sb + q1], b1 = embr[sb + q1 + 64];
        float4 a2 = embr[sb + q2], b2 = embr[sb + q2 + 64];
        float4 a3 = embr[sb + q3], b3 = embr[sb + q3 + 64];
        __builtin_amdgcn_sched_barrier(0);  // loads stay above the math

        // rows beyond wmax: weight forced to 0 (their lane index wrapped
        // by &31 would alias a valid weight, so the select is required).
        const float t0 = __shfl(wt, r0 & 31, 64);
        const float t1 = (r0 + 1 <= wmax) ? __shfl(wt, (r0 + 1) & 31, 64) : 0.f;
        const float t2 = (r0 + 2 <= wmax) ? __shfl(wt, (r0 + 2) & 31, 64) : 0.f;
        const float t3 = (r0 + 3 <= wmax) ? __shfl(wt, (r0 + 3) & 31, 64) : 0.f;
        acc0.x += t0*a0.x + t1*a1.x + t2*a2.x + t3*a3.x;
        acc0.y += t0*a0.y + t1*a1.y + t2*a2.y + t3*a3.y;
        acc0.z += t0*a0.z + t1*a1.z + t2*a2.z + t3*a3.z;
        acc0.w += t0*a0.w + t1*a1.w + t2*a2.w + t3*a3.w;
        acc1.x += t0*b0.x + t1*b1.x + t2*b2.x + t3*b3.x;
        acc1.y += t0*b0.y + t1*b1.y + t2*b2.y + t3*b3.y;
        acc1.z += t0*b0.z + t1*b1.z + t2*b2.z + t3*b3.z;
        acc1.w += t0*b0.w + t1*b1.w + t2*b2.w + t3*b3.w;
    }

    // ---- end row: re-load (L1-hot, last group just touched it) -----------
    const size_t eb = sb + (size_t)wmax * 256;
    float4 ev0 = embr[eb];
    float4 ev1 = embr[eb + 64];

    // ---- stores (all coalesced: 64 lanes x 16 B contiguous) --------------
    float4* __restrict__ o4 = (float4*)out + (size_t)s * 768;
    o4[basecol]            = sv0;
    o4[basecol + 64]       = sv1;
    o4[256 + basecol]      = ev0;
    o4[256 + basecol + 64] = ev1;
    o4[512 + basecol]      = acc0;
    o4[512 + basecol + 64] = acc1;
}

extern "C" void kernel_launch(void* const* d_in, const int* in_sizes, int n_in,
                              void* d_out, int out_size, void* d_ws, size_t ws_size,
                              hipStream_t stream) {
    const float* emb    = (const float*)d_in[0];
    const int*   starts = (const int*)d_in[1];
    const int*   ends   = (const int*)d_in[2];
    const float* attn_w = (const float*)d_in[3];
    const float* attn_b = (const float*)d_in[4];
    float* out   = (float*)d_out;
    float* s_all = (float*)d_ws;        // 8192 floats = 32 KB scratch

    row_score_kernel<<<SEQ_LEN / 4, 256, 0, stream>>>(emb, attn_w, attn_b, s_all);
    span_out_kernel<<<NUM_SPANS / 2, 256, 0, stream>>>(emb, starts, ends, s_all, out);
}